// Round 9
// baseline (648.905 us; speedup 1.0000x reference)
//
#include <hip/hip_runtime.h>
#include <hip/hip_bf16.h>
#include <stdint.h>

// GnnActor fused deepset actor. INPUTS/OUTPUTS ARE FLOAT32 (reference dtype).
// v7 (prefetch-distance-2 pipeline) — 2nd resubmission; rounds 7 and 8 both
// hit GPU acquisition timeouts, so this kernel has never been measured.
//  - edge/obj loads for node n+2 issue at the TOP of iteration n and are
//    consumed (segmax-reduce -> As stage) in iteration n+1 -> a full
//    iteration (~GEMM1+GEMM2) of latency cover for the 900-cyc HBM stream
//    (v6 covered only ~GEMM1, exposing ~700 cyc/node at 2 waves/SIMD).
//  - two NAMED register prefetch buffers (pfA/pfB), pair-unrolled node loop
//    (static buffer binding; no runtime-indexed reg arrays -> no scratch).
//  - W2 residency DROPPED to pay for the second buffer (-64 VGPR): GEMM2
//    streams B from L2/L1 (16x16B per node per wave, ~100cy exposure).
//    W1 (80 VGPR) stays resident - it covers the load-issue region.
//  - everything else as v6: 512-thr blocks, 8 waves x 32 cols, grid 512,
//    single As buffer (write-after-S1 / read-after-S2), fused rho+heads.
// Scratch in module __device__ arrays (no d_ws use; graph-safe).

#define Bsz   8192
#define OBSW  1216      // 64 + 9*128
#define NH    256

typedef unsigned short u16;
typedef unsigned int   u32;

using bf16x8 = __attribute__((ext_vector_type(8))) short;
using f32x4  = __attribute__((ext_vector_type(4))) float;

// ---- module-scope scratch (~0.6 MB .bss) ----
__device__ __attribute__((aligned(16))) u16 g_W1t[256 * 320];   // bf16(W1)^T
__device__ __attribute__((aligned(16))) u16 g_W2t[256 * 256];   // bf16(W2)^T
__device__ __attribute__((aligned(16))) u16 g_Rt [256 * 256];   // bf16(Wrho)^T
__device__ __attribute__((aligned(16))) u16 g_Wcat[64 * 256];   // [Wm^T ; Ws^T]

__device__ __forceinline__ u16 f2bf(float f) {
  union { float f; u32 i; } v; v.f = f;
  u32 x = v.i;
  x += 0x7fffu + ((x >> 16) & 1u);   // RNE; values here are finite
  return (u16)(x >> 16);
}
__device__ __forceinline__ ushort4 pack4(float4 f) {
  ushort4 o = { f2bf(f.x), f2bf(f.y), f2bf(f.z), f2bf(f.w) };
  return o;
}

struct PF { float4 pe[8]; float4 pa; float4 ps; };   // per-thread prefetch buf

// ---------------- weight transpose+cast (one small launch) ---------------------
// f32 in[K][N] -> bf16 out[N][K]; 224 blocks cover W1|W2|Wr|Wm|Ws.
__global__ __launch_bounds__(256)
void transpose_all(const float* __restrict__ W1, const float* __restrict__ W2,
                   const float* __restrict__ Wr, const float* __restrict__ Wm,
                   const float* __restrict__ Wsg) {
  __shared__ u16 tile[32][33];
  int bx = blockIdx.x;
  const float* in; u16* out; int K, N, row_off = 0, k0, n0;
  if (bx < 80)       { in = W1;  out = g_W1t;  K = 320; N = 256; k0 = (bx % 10) * 32; n0 = (bx / 10) * 32; }
  else if (bx < 144) { bx -= 80;  in = W2;  out = g_W2t;  K = 256; N = 256; k0 = (bx & 7) * 32; n0 = (bx >> 3) * 32; }
  else if (bx < 208) { bx -= 144; in = Wr;  out = g_Rt;   K = 256; N = 256; k0 = (bx & 7) * 32; n0 = (bx >> 3) * 32; }
  else if (bx < 216) { bx -= 208; in = Wm;  out = g_Wcat; K = 256; N = 32;  k0 = bx * 32; n0 = 0; }
  else               { bx -= 216; in = Wsg; out = g_Wcat; K = 256; N = 32;  k0 = bx * 32; n0 = 0; row_off = 32; }
  int c = threadIdx.x & 31, r0 = threadIdx.x >> 5;
  #pragma unroll
  for (int i = 0; i < 4; i++) {
    int r = r0 + i * 8;
    tile[r][c] = f2bf(in[(size_t)(k0 + r) * N + (n0 + c)]);
  }
  __syncthreads();
  #pragma unroll
  for (int i = 0; i < 4; i++) {
    int r = r0 + i * 8;
    out[(size_t)(n0 + r + row_off) * K + (k0 + c)] = tile[c][r];
  }
}

// issue loads for node n2 into buffer d (no waits here)
__device__ __forceinline__ void issueL(int n2, size_t ar, int dq4,
    const float* __restrict__ obs, const float* __restrict__ ef,
    const float* __restrict__ iso, const float* __restrict__ isof, PF& d) {
  if (n2 < 9) {
    d.pa = *(const float4*)(obs + ar * OBSW + 64 + (size_t)n2 * 128 + dq4);
    const float* base = ef + (ar * 72 + n2) * 128 + dq4;   // edge e = n2 + 9j
    #pragma unroll
    for (int j = 0; j < 8; j++)
      d.pe[j] = *(const float4*)(base + (size_t)j * 1152);
  } else {
    d.pa = *(const float4*)(iso  + (ar * 3 + (n2 - 9)) * 128 + dq4);
    d.ps = *(const float4*)(isof + (ar * 3 + (n2 - 9)) * 128 + dq4);
  }
}

// segmax-reduce buffer c and stage As cols for node n1 (waits on c's loads)
__device__ __forceinline__ void stageA(int n1, int sr, int dq4, PF& c,
                                       u16 (*As)[328]) {
  *(ushort4*)(&As[sr][64 + dq4]) = pack4(c.pa);
  if (n1 < 9) {
    float4 m01, m23, m45, m67, ma, mb, m;
    m01.x = fmaxf(c.pe[0].x, c.pe[1].x); m01.y = fmaxf(c.pe[0].y, c.pe[1].y);
    m01.z = fmaxf(c.pe[0].z, c.pe[1].z); m01.w = fmaxf(c.pe[0].w, c.pe[1].w);
    m23.x = fmaxf(c.pe[2].x, c.pe[3].x); m23.y = fmaxf(c.pe[2].y, c.pe[3].y);
    m23.z = fmaxf(c.pe[2].z, c.pe[3].z); m23.w = fmaxf(c.pe[2].w, c.pe[3].w);
    m45.x = fmaxf(c.pe[4].x, c.pe[5].x); m45.y = fmaxf(c.pe[4].y, c.pe[5].y);
    m45.z = fmaxf(c.pe[4].z, c.pe[5].z); m45.w = fmaxf(c.pe[4].w, c.pe[5].w);
    m67.x = fmaxf(c.pe[6].x, c.pe[7].x); m67.y = fmaxf(c.pe[6].y, c.pe[7].y);
    m67.z = fmaxf(c.pe[6].z, c.pe[7].z); m67.w = fmaxf(c.pe[6].w, c.pe[7].w);
    ma.x = fmaxf(m01.x, m23.x); ma.y = fmaxf(m01.y, m23.y);
    ma.z = fmaxf(m01.z, m23.z); ma.w = fmaxf(m01.w, m23.w);
    mb.x = fmaxf(m45.x, m67.x); mb.y = fmaxf(m45.y, m67.y);
    mb.z = fmaxf(m45.z, m67.z); mb.w = fmaxf(m45.w, m67.w);
    m.x = fmaxf(ma.x, mb.x); m.y = fmaxf(ma.y, mb.y);
    m.z = fmaxf(ma.z, mb.z); m.w = fmaxf(ma.w, mb.w);
    *(ushort4*)(&As[sr][192 + dq4]) = pack4(m);
  } else {
    *(ushort4*)(&As[sr][192 + dq4]) = pack4(c.ps);
  }
}

// ---------------- fused stream + node + rho + heads kernel ---------------------
// grid = Bsz/16 = 512, 512 threads (8 waves, 32 output cols each).
__global__ __launch_bounds__(512, 2)
void node_kernel(const float* __restrict__ obs, const float* __restrict__ ef,
                 const float* __restrict__ iso, const float* __restrict__ isof,
                 const float* __restrict__ b1, const float* __restrict__ b2,
                 const float* __restrict__ br, const float* __restrict__ bm,
                 const float* __restrict__ bs, float* __restrict__ out) {
  __shared__ __attribute__((aligned(16))) u16 As[16][328];  // 16x320 A-tile
  __shared__ __attribute__((aligned(16))) u16 Ht[16][264];  // 16x256 hidden
  const int b0 = blockIdx.x * 16;
  const int tid = threadIdx.x;
  const int wave = tid >> 6, lane = tid & 63;
  const int w32 = wave * 32, lrow = lane & 15, quad = lane >> 4;
  const int sr = tid >> 5, sc = tid & 31, dq4 = sc * 4;   // staging map
  const size_t ar = (size_t)(b0 + sr);                    // staging row

  // ---- resident B fragments: W1^T only (80 VGPR/wave) ----------------------
  bf16x8 w1f[10][2];   // [kc][nb]
  #pragma unroll
  for (int kc = 0; kc < 10; kc++)
    #pragma unroll
    for (int nb = 0; nb < 2; nb++)
      w1f[kc][nb] = *(const bf16x8*)(g_W1t + (size_t)(w32 + nb * 16 + lrow) * 320
                                     + kc * 32 + quad * 8);
  // per-wave W2^T row pointers (streamed from L1/L2 in GEMM2)
  const u16* w2r0 = g_W2t + (size_t)(w32 + lrow) * 256 + quad * 8;
  const u16* w2r1 = g_W2t + (size_t)(w32 + 16 + lrow) * 256 + quad * 8;

  float bv1[2], bv2[2];
  #pragma unroll
  for (int nb = 0; nb < 2; nb++) {
    int col = w32 + nb * 16 + lrow;
    bv1[nb] = b1[col]; bv2[nb] = b2[col];
  }

  const f32x4 vzero = {0.f, 0.f, 0.f, 0.f};
  f32x4 pool[2] = {vzero, vzero};
  PF pfA, pfB;   // L(even) -> pfA, L(odd) -> pfB

  // ---- prologue: body cols + L(0) -> stage As(0); L(1) stays in flight -----
  {
    float4 fb;
    if (sc < 16) fb = *(const float4*)(obs + ar * OBSW + dq4);  // body 0..63
    issueL(0, ar, dq4, obs, ef, iso, isof, pfA);
    issueL(1, ar, dq4, obs, ef, iso, isof, pfB);
    if (sc < 16) *(ushort4*)(&As[sr][dq4]) = pack4(fb);
    stageA(0, sr, dq4, pfA, As);   // waits pfA only (pfB stays outstanding)
  }
  __syncthreads();   // As(0) ready

  // one node iteration; cons holds L(n+1), iss receives L(n+2)
  auto node_iter = [&](int n, PF& cons, PF& iss) {
    if (n + 2 < 12) issueL(n + 2, ar, dq4, obs, ef, iso, isof, iss);

    // ---- GEMM1: K=320, A from As (LDS), B resident — no memory stalls ------
    f32x4 acc[2] = {vzero, vzero};
    #pragma unroll
    for (int kc = 0; kc < 10; kc++) {
      bf16x8 af = *(const bf16x8*)(&As[lrow][kc * 32 + quad * 8]);
      #pragma unroll
      for (int nb = 0; nb < 2; nb++)
        acc[nb] = __builtin_amdgcn_mfma_f32_16x16x32_bf16(af, w1f[kc][nb],
                                                          acc[nb], 0, 0, 0);
    }
    // epilogue 1: Ht = bf16(relu(acc + b1))  (Ht readers done at S2(n-1))
    #pragma unroll
    for (int nb = 0; nb < 2; nb++) {
      int col = w32 + nb * 16 + lrow;
      #pragma unroll
      for (int i = 0; i < 4; i++)
        Ht[quad * 4 + i][col] = f2bf(fmaxf(acc[nb][i] + bv1[nb], 0.f));
    }
    __syncthreads();   // S1: Ht(n) ready; As(n) GEMM1 reads retired

    // ---- consume L(n+1): segmax reduce -> stage As(n+1) --------------------
    if (n + 1 < 12) stageA(n + 1, sr, dq4, cons, As);

    // ---- GEMM2: K=256, A from Ht (LDS), B streamed (L1/L2-hot) -------------
    f32x4 acc2[2] = {vzero, vzero};
    #pragma unroll
    for (int kc = 0; kc < 8; kc++) {
      bf16x8 af  = *(const bf16x8*)(&Ht[lrow][kc * 32 + quad * 8]);
      bf16x8 bq0 = *(const bf16x8*)(w2r0 + kc * 32);
      bf16x8 bq1 = *(const bf16x8*)(w2r1 + kc * 32);
      acc2[0] = __builtin_amdgcn_mfma_f32_16x16x32_bf16(af, bq0, acc2[0], 0, 0, 0);
      acc2[1] = __builtin_amdgcn_mfma_f32_16x16x32_bf16(af, bq1, acc2[1], 0, 0, 0);
    }
    // epilogue 2: pool += relu(acc + b2)
    #pragma unroll
    for (int nb = 0; nb < 2; nb++)
      #pragma unroll
      for (int i = 0; i < 4; i++)
        pool[nb][i] += fmaxf(acc2[nb][i] + bv2[nb], 0.f);
    __syncthreads();   // S2: As(n+1) visible; Ht(n) reads done
  };

  // pair-unrolled node loop: static pfA/pfB binding per parity
  for (int n = 0; n < 12; n += 2) {
    node_iter(n,     pfB, pfA);   // consume L(n+1) from pfB, issue L(n+2)->pfA
    node_iter(n + 1, pfA, pfB);   // consume L(n+2) from pfA, issue L(n+3)->pfB
  }

  // ---- rho: pooled -> bf16 A-tile (reuse Ht) -> GEMM3(relu,br) -------------
  #pragma unroll
  for (int nb = 0; nb < 2; nb++) {
    int col = w32 + nb * 16 + lrow;
    #pragma unroll
    for (int i = 0; i < 4; i++)
      Ht[quad * 4 + i][col] = f2bf(pool[nb][i]);
  }
  __syncthreads();

  f32x4 acc3[2] = {vzero, vzero};
  #pragma unroll
  for (int kc = 0; kc < 8; kc++) {
    bf16x8 af = *(const bf16x8*)(&Ht[lrow][kc * 32 + quad * 8]);
    #pragma unroll
    for (int nb = 0; nb < 2; nb++) {
      bf16x8 bq = *(const bf16x8*)(g_Rt + (size_t)(w32 + nb * 16 + lrow) * 256
                                   + kc * 32 + quad * 8);
      acc3[nb] = __builtin_amdgcn_mfma_f32_16x16x32_bf16(af, bq, acc3[nb], 0, 0, 0);
    }
  }
  __syncthreads();   // Ht reads done
  #pragma unroll
  for (int nb = 0; nb < 2; nb++) {
    int col = w32 + nb * 16 + lrow;
    float bv = br[col];
    #pragma unroll
    for (int i = 0; i < 4; i++)
      Ht[quad * 4 + i][col] = f2bf(fmaxf(acc3[nb][i] + bv, 0.f));
  }
  __syncthreads();   // r visible

  // ---- heads: N=64 (mean|log_std); waves 0..3 own 16-col tiles -------------
  if (wave < 4) {
    f32x4 acch = vzero;
    #pragma unroll
    for (int kc = 0; kc < 8; kc++) {
      bf16x8 af = *(const bf16x8*)(&Ht[lrow][kc * 32 + quad * 8]);
      bf16x8 bq = *(const bf16x8*)(g_Wcat + (size_t)(wave * 16 + lrow) * 256
                                   + kc * 32 + quad * 8);
      acch = __builtin_amdgcn_mfma_f32_16x16x32_bf16(af, bq, acch, 0, 0, 0);
    }
    int j = wave * 16 + lrow;
    #pragma unroll
    for (int i = 0; i < 4; i++) {
      int b = b0 + quad * 4 + i;
      if (j < 32) {
        out[(size_t)b * 32 + j] = acch[i] + bm[j];
      } else {
        float v = acch[i] + bs[j - 32];
        v = fminf(fmaxf(v, -20.f), 2.f);
        out[(size_t)Bsz * 32 + (size_t)b * 32 + (j - 32)] = v;
      }
    }
  }
}

extern "C" void kernel_launch(void* const* d_in, const int* in_sizes, int n_in,
                              void* d_out, int out_size, void* d_ws, size_t ws_size,
                              hipStream_t stream) {
  const float* obs  = (const float*)d_in[0];
  const float* ef   = (const float*)d_in[1];
  // d_in[2] = edges_to (int32): tile(arange(9),8) -> edge e feeds node e%9
  const float* iso  = (const float*)d_in[3];
  const float* isof = (const float*)d_in[4];
  const float* W1   = (const float*)d_in[5];
  const float* b1   = (const float*)d_in[6];
  const float* W2   = (const float*)d_in[7];
  const float* b2   = (const float*)d_in[8];
  const float* Wr   = (const float*)d_in[9];
  const float* br   = (const float*)d_in[10];
  const float* Wm   = (const float*)d_in[11];
  const float* bm   = (const float*)d_in[12];
  const float* Wsg  = (const float*)d_in[13];
  const float* bs   = (const float*)d_in[14];
  float* out = (float*)d_out;
  (void)d_ws; (void)ws_size;

  transpose_all<<<224, 256, 0, stream>>>(W1, W2, Wr, Wm, Wsg);
  node_kernel<<<Bsz / 16, 512, 0, stream>>>(obs, ef, iso, isof,
                                            b1, b2, br, bm, bs, out);
}

// Round 10
// 550.934 us; speedup vs baseline: 1.1778x; 1.1778x over previous
//
#include <hip/hip_runtime.h>
#include <hip/hip_bf16.h>
#include <stdint.h>

// GnnActor fused deepset actor. INPUTS/OUTPUTS ARE FLOAT32 (reference dtype).
// v8 (spill-proof prefetch-distance-2):
//  - v7's pipeline REGRESSED (node 316us, VGPR 84, WRITE_SIZE 357MB): the PF
//    structs passed as lambda reference params were demoted to scratch
//    (rule-#20 class failure). Same schedule, reimplemented spill-proof:
//    NO structs, NO lambdas — prefetch buffers are individually named float4
//    registers (peA0..7/paA/psA, peB0..7/paB/psB) and the 12-node loop is
//    macro-instantiated with STATIC buffer-suffix binding.
//  - schedule per node n: ISSUE L(n+2) -> GEMM1(n) -> epi1 -> S1 ->
//    STAGE L(n+1) (segmax reduce, first use of those loads => full-iteration
//    latency cover) -> GEMM2(n) -> epi2 -> S2.
//  - W1^T resident (80 VGPR/wave); W2^T streamed from L1/L2 (16B x 16/node).
//  - 512-thr blocks, 8 waves x 32 output cols, grid 512, fused rho+heads.
// Scratch in module __device__ arrays (no d_ws use; graph-safe).

#define Bsz   8192
#define OBSW  1216      // 64 + 9*128
#define NH    256

typedef unsigned short u16;
typedef unsigned int   u32;

using bf16x8 = __attribute__((ext_vector_type(8))) short;
using f32x4  = __attribute__((ext_vector_type(4))) float;

// ---- module-scope scratch (~0.6 MB .bss) ----
__device__ __attribute__((aligned(16))) u16 g_W1t[256 * 320];   // bf16(W1)^T
__device__ __attribute__((aligned(16))) u16 g_W2t[256 * 256];   // bf16(W2)^T
__device__ __attribute__((aligned(16))) u16 g_Rt [256 * 256];   // bf16(Wrho)^T
__device__ __attribute__((aligned(16))) u16 g_Wcat[64 * 256];   // [Wm^T ; Ws^T]

__device__ __forceinline__ u16 f2bf(float f) {
  union { float f; u32 i; } v; v.f = f;
  u32 x = v.i;
  x += 0x7fffu + ((x >> 16) & 1u);   // RNE; values here are finite
  return (u16)(x >> 16);
}
__device__ __forceinline__ ushort4 pack4(float4 f) {
  ushort4 o = { f2bf(f.x), f2bf(f.y), f2bf(f.z), f2bf(f.w) };
  return o;
}
__device__ __forceinline__ float4 vmax4(float4 a, float4 b) {
  float4 r;
  r.x = fmaxf(a.x, b.x); r.y = fmaxf(a.y, b.y);
  r.z = fmaxf(a.z, b.z); r.w = fmaxf(a.w, b.w);
  return r;
}

// ---------------- weight transpose+cast (one small launch) ---------------------
// f32 in[K][N] -> bf16 out[N][K]; 224 blocks cover W1|W2|Wr|Wm|Ws.
__global__ __launch_bounds__(256)
void transpose_all(const float* __restrict__ W1, const float* __restrict__ W2,
                   const float* __restrict__ Wr, const float* __restrict__ Wm,
                   const float* __restrict__ Wsg) {
  __shared__ u16 tile[32][33];
  int bx = blockIdx.x;
  const float* in; u16* out; int K, N, row_off = 0, k0, n0;
  if (bx < 80)       { in = W1;  out = g_W1t;  K = 320; N = 256; k0 = (bx % 10) * 32; n0 = (bx / 10) * 32; }
  else if (bx < 144) { bx -= 80;  in = W2;  out = g_W2t;  K = 256; N = 256; k0 = (bx & 7) * 32; n0 = (bx >> 3) * 32; }
  else if (bx < 208) { bx -= 144; in = Wr;  out = g_Rt;   K = 256; N = 256; k0 = (bx & 7) * 32; n0 = (bx >> 3) * 32; }
  else if (bx < 216) { bx -= 208; in = Wm;  out = g_Wcat; K = 256; N = 32;  k0 = bx * 32; n0 = 0; }
  else               { bx -= 216; in = Wsg; out = g_Wcat; K = 256; N = 32;  k0 = bx * 32; n0 = 0; row_off = 32; }
  int c = threadIdx.x & 31, r0 = threadIdx.x >> 5;
  #pragma unroll
  for (int i = 0; i < 4; i++) {
    int r = r0 + i * 8;
    tile[r][c] = f2bf(in[(size_t)(k0 + r) * N + (n0 + c)]);
  }
  __syncthreads();
  #pragma unroll
  for (int i = 0; i < 4; i++) {
    int r = r0 + i * 8;
    out[(size_t)(n0 + r + row_off) * K + (k0 + c)] = tile[c][r];
  }
}

// ---- spill-proof pipeline macros (all indices compile-time constants) ---------
#define ISSUE(S, n2) do {                                                      \
    if ((n2) < 9) {                                                            \
      pa##S = *(const float4*)(obs + ar * OBSW + 64 + (size_t)(n2) * 128 + dq4); \
      const float* base_ = ef + (ar * 72 + (n2)) * 128 + dq4;                  \
      pe##S##0 = *(const float4*)(base_);                                      \
      pe##S##1 = *(const float4*)(base_ + 1152);                               \
      pe##S##2 = *(const float4*)(base_ + 2304);                               \
      pe##S##3 = *(const float4*)(base_ + 3456);                               \
      pe##S##4 = *(const float4*)(base_ + 4608);                               \
      pe##S##5 = *(const float4*)(base_ + 5760);                               \
      pe##S##6 = *(const float4*)(base_ + 6912);                               \
      pe##S##7 = *(const float4*)(base_ + 8064);                               \
    } else {                                                                   \
      pa##S = *(const float4*)(iso  + (ar * 3 + ((n2) - 9)) * 128 + dq4);      \
      ps##S = *(const float4*)(isof + (ar * 3 + ((n2) - 9)) * 128 + dq4);      \
    }                                                                          \
  } while (0)

#define STAGE(S, n1) do {                                                      \
    *(ushort4*)(&As[sr][64 + dq4]) = pack4(pa##S);                             \
    if ((n1) < 9) {                                                            \
      float4 m_ = vmax4(vmax4(vmax4(pe##S##0, pe##S##1),                       \
                              vmax4(pe##S##2, pe##S##3)),                      \
                        vmax4(vmax4(pe##S##4, pe##S##5),                       \
                              vmax4(pe##S##6, pe##S##7)));                     \
      *(ushort4*)(&As[sr][192 + dq4]) = pack4(m_);                             \
    } else {                                                                   \
      *(ushort4*)(&As[sr][192 + dq4]) = pack4(ps##S);                          \
    }                                                                          \
  } while (0)

#define GEMM1_EPI1() do {                                                      \
    f32x4 a0_ = vzero, a1_ = vzero;                                            \
    _Pragma("unroll")                                                          \
    for (int kc = 0; kc < 10; kc++) {                                          \
      bf16x8 af_ = *(const bf16x8*)(&As[lrow][kc * 32 + quad * 8]);            \
      a0_ = __builtin_amdgcn_mfma_f32_16x16x32_bf16(af_, w1f[kc][0], a0_, 0, 0, 0); \
      a1_ = __builtin_amdgcn_mfma_f32_16x16x32_bf16(af_, w1f[kc][1], a1_, 0, 0, 0); \
    }                                                                          \
    _Pragma("unroll")                                                          \
    for (int i = 0; i < 4; i++) {                                              \
      Ht[quad * 4 + i][w32 + lrow]      = f2bf(fmaxf(a0_[i] + bv1[0], 0.f));   \
      Ht[quad * 4 + i][w32 + 16 + lrow] = f2bf(fmaxf(a1_[i] + bv1[1], 0.f));   \
    }                                                                          \
  } while (0)

#define GEMM2_EPI2() do {                                                      \
    f32x4 c0_ = vzero, c1_ = vzero;                                            \
    _Pragma("unroll")                                                          \
    for (int kc = 0; kc < 8; kc++) {                                           \
      bf16x8 af_ = *(const bf16x8*)(&Ht[lrow][kc * 32 + quad * 8]);            \
      bf16x8 b0_ = *(const bf16x8*)(w2r0 + kc * 32);                           \
      bf16x8 b1_ = *(const bf16x8*)(w2r1 + kc * 32);                           \
      c0_ = __builtin_amdgcn_mfma_f32_16x16x32_bf16(af_, b0_, c0_, 0, 0, 0);   \
      c1_ = __builtin_amdgcn_mfma_f32_16x16x32_bf16(af_, b1_, c1_, 0, 0, 0);   \
    }                                                                          \
    _Pragma("unroll")                                                          \
    for (int i = 0; i < 4; i++) {                                              \
      pool[0][i] += fmaxf(c0_[i] + bv2[0], 0.f);                               \
      pool[1][i] += fmaxf(c1_[i] + bv2[1], 0.f);                               \
    }                                                                          \
  } while (0)

// node n: issue L(n+2) into ISS, compute GEMM1(n), stage L(n+1) from CONS,
// compute GEMM2(n). All guards fold at compile time (n is a literal).
#define NODE(n, ISS, CONS) do {                                                \
    if ((n) + 2 < 12) ISSUE(ISS, (n) + 2);                                     \
    GEMM1_EPI1();                                                              \
    __syncthreads();   /* S1: Ht(n) ready; As(n) GEMM1 reads retired */        \
    if ((n) + 1 < 12) STAGE(CONS, (n) + 1);                                    \
    GEMM2_EPI2();                                                              \
    __syncthreads();   /* S2: As(n+1) visible; Ht(n) reads done */             \
  } while (0)

// ---------------- fused stream + node + rho + heads kernel ---------------------
// grid = Bsz/16 = 512, 512 threads (8 waves, 32 output cols each).
__global__ __launch_bounds__(512, 2)
void node_kernel(const float* __restrict__ obs, const float* __restrict__ ef,
                 const float* __restrict__ iso, const float* __restrict__ isof,
                 const float* __restrict__ b1, const float* __restrict__ b2,
                 const float* __restrict__ br, const float* __restrict__ bm,
                 const float* __restrict__ bs, float* __restrict__ out) {
  __shared__ __attribute__((aligned(16))) u16 As[16][328];  // 16x320 A-tile
  __shared__ __attribute__((aligned(16))) u16 Ht[16][264];  // 16x256 hidden
  const int b0 = blockIdx.x * 16;
  const int tid = threadIdx.x;
  const int wave = tid >> 6, lane = tid & 63;
  const int w32 = wave * 32, lrow = lane & 15, quad = lane >> 4;
  const int sr = tid >> 5, sc = tid & 31, dq4 = sc * 4;   // staging map
  const size_t ar = (size_t)(b0 + sr);                    // staging row

  // ---- resident B fragments: W1^T only (80 VGPR/wave) ----------------------
  bf16x8 w1f[10][2];   // [kc][nb] — statically indexed everywhere
  #pragma unroll
  for (int kc = 0; kc < 10; kc++)
    #pragma unroll
    for (int nb = 0; nb < 2; nb++)
      w1f[kc][nb] = *(const bf16x8*)(g_W1t + (size_t)(w32 + nb * 16 + lrow) * 320
                                     + kc * 32 + quad * 8);
  // per-wave W2^T row pointers (streamed from L1/L2 in GEMM2)
  const u16* w2r0 = g_W2t + (size_t)(w32 + lrow) * 256 + quad * 8;
  const u16* w2r1 = g_W2t + (size_t)(w32 + 16 + lrow) * 256 + quad * 8;

  float bv1[2], bv2[2];
  #pragma unroll
  for (int nb = 0; nb < 2; nb++) {
    int col = w32 + nb * 16 + lrow;
    bv1[nb] = b1[col]; bv2[nb] = b2[col];
  }

  const f32x4 vzero = {0.f, 0.f, 0.f, 0.f};
  f32x4 pool[2] = {vzero, vzero};

  // ---- named prefetch registers (NO aggregates -> cannot be demoted) -------
  float4 peA0, peA1, peA2, peA3, peA4, peA5, peA6, peA7, paA, psA;
  float4 peB0, peB1, peB2, peB3, peB4, peB5, peB6, peB7, paB, psB;

  // ---- prologue: body cols + L(0)->A, L(1)->B; stage As(0) from A ----------
  {
    float4 fb;
    if (sc < 16) fb = *(const float4*)(obs + ar * OBSW + dq4);  // body 0..63
    ISSUE(A, 0);
    ISSUE(B, 1);
    if (sc < 16) *(ushort4*)(&As[sr][dq4]) = pack4(fb);
    STAGE(A, 0);   // waits A's loads only; B stays outstanding
  }
  __syncthreads();   // As(0) ready

  // L(even)->A, L(odd)->B; NODE(even): iss A / cons B, NODE(odd): iss B / cons A
  NODE(0, A, B);   NODE(1, B, A);
  NODE(2, A, B);   NODE(3, B, A);
  NODE(4, A, B);   NODE(5, B, A);
  NODE(6, A, B);   NODE(7, B, A);
  NODE(8, A, B);   NODE(9, B, A);
  NODE(10, A, B);  NODE(11, B, A);

  // ---- rho: pooled -> bf16 A-tile (reuse Ht) -> GEMM3(relu,br) -------------
  #pragma unroll
  for (int nb = 0; nb < 2; nb++) {
    int col = w32 + nb * 16 + lrow;
    #pragma unroll
    for (int i = 0; i < 4; i++)
      Ht[quad * 4 + i][col] = f2bf(pool[nb][i]);
  }
  __syncthreads();

  f32x4 acc3[2] = {vzero, vzero};
  #pragma unroll
  for (int kc = 0; kc < 8; kc++) {
    bf16x8 af = *(const bf16x8*)(&Ht[lrow][kc * 32 + quad * 8]);
    #pragma unroll
    for (int nb = 0; nb < 2; nb++) {
      bf16x8 bq = *(const bf16x8*)(g_Rt + (size_t)(w32 + nb * 16 + lrow) * 256
                                   + kc * 32 + quad * 8);
      acc3[nb] = __builtin_amdgcn_mfma_f32_16x16x32_bf16(af, bq, acc3[nb], 0, 0, 0);
    }
  }
  __syncthreads();   // Ht reads done
  #pragma unroll
  for (int nb = 0; nb < 2; nb++) {
    int col = w32 + nb * 16 + lrow;
    float bv = br[col];
    #pragma unroll
    for (int i = 0; i < 4; i++)
      Ht[quad * 4 + i][col] = f2bf(fmaxf(acc3[nb][i] + bv, 0.f));
  }
  __syncthreads();   // r visible

  // ---- heads: N=64 (mean|log_std); waves 0..3 own 16-col tiles -------------
  if (wave < 4) {
    f32x4 acch = vzero;
    #pragma unroll
    for (int kc = 0; kc < 8; kc++) {
      bf16x8 af = *(const bf16x8*)(&Ht[lrow][kc * 32 + quad * 8]);
      bf16x8 bq = *(const bf16x8*)(g_Wcat + (size_t)(wave * 16 + lrow) * 256
                                   + kc * 32 + quad * 8);
      acch = __builtin_amdgcn_mfma_f32_16x16x32_bf16(af, bq, acch, 0, 0, 0);
    }
    int j = wave * 16 + lrow;
    #pragma unroll
    for (int i = 0; i < 4; i++) {
      int b = b0 + quad * 4 + i;
      if (j < 32) {
        out[(size_t)b * 32 + j] = acch[i] + bm[j];
      } else {
        float v = acch[i] + bs[j - 32];
        v = fminf(fmaxf(v, -20.f), 2.f);
        out[(size_t)Bsz * 32 + (size_t)b * 32 + (j - 32)] = v;
      }
    }
  }
}

extern "C" void kernel_launch(void* const* d_in, const int* in_sizes, int n_in,
                              void* d_out, int out_size, void* d_ws, size_t ws_size,
                              hipStream_t stream) {
  const float* obs  = (const float*)d_in[0];
  const float* ef   = (const float*)d_in[1];
  // d_in[2] = edges_to (int32): tile(arange(9),8) -> edge e feeds node e%9
  const float* iso  = (const float*)d_in[3];
  const float* isof = (const float*)d_in[4];
  const float* W1   = (const float*)d_in[5];
  const float* b1   = (const float*)d_in[6];
  const float* W2   = (const float*)d_in[7];
  const float* b2   = (const float*)d_in[8];
  const float* Wr   = (const float*)d_in[9];
  const float* br   = (const float*)d_in[10];
  const float* Wm   = (const float*)d_in[11];
  const float* bm   = (const float*)d_in[12];
  const float* Wsg  = (const float*)d_in[13];
  const float* bs   = (const float*)d_in[14];
  float* out = (float*)d_out;
  (void)d_ws; (void)ws_size;

  transpose_all<<<224, 256, 0, stream>>>(W1, W2, Wr, Wm, Wsg);
  node_kernel<<<Bsz / 16, 512, 0, stream>>>(obs, ef, iso, isof,
                                            b1, b2, br, bm, bs, out);
}